// Round 1
// 555.201 us; speedup vs baseline: 1.0005x; 1.0005x over previous
//
#include <hip/hip_runtime.h>
#include <math.h>

// Problem constants
#define BB   8
#define NB   300
#define RSEL 36
#define NCH  256
#define NW   10          // ceil(300/32) bitmask words
#define IOU_THR  0.7f
#define CONF_THR 0.3f
#define WSTR 128         // floats per (b,roi) ws record

// ws record layout (per (b, slot<36), stride WSTR floats):
//  [0] valid (1/0)   [1] level (0..3)  [2] nr (# distinct rows)
//  [3] ce (col extent in the stored window frame, <=64)
//  [4] xs (window base col; for lvl<=1 it is 4-aligned and end-clamped so
//          [xs, xs+64) always lies fully inside the row -> float4-safe)
//  [8..35]  row indices (float)        [36..63] row weights (incl 1/196)
//  [64..127] dense column weights wxd[64] relative to xs

#define NMS_T 1024

__global__ __launch_bounds__(NMS_T) void nms_kernel(
    const float* __restrict__ boxes, const float* __restrict__ scores,
    float* __restrict__ ws)
{
    const int b   = blockIdx.x;
    const int tid = threadIdx.x;

    __shared__ float ss[NB];            // thresholded scores, original order
    __shared__ float sbx[NB][4];        // boxes in sorted order
    __shared__ unsigned int supp[NB][NW];
    __shared__ unsigned int keepw[NW];
    __shared__ int kept_total;

    const float NEG_INF = -__builtin_inff();

    // 0) cooperative zero of this batch's ws records (global, coalesced)
    {
        float* wb = ws + (size_t)b * RSEL * WSTR;
        for (int t = tid; t < RSEL * WSTR; t += NMS_T) wb[t] = 0.0f;
    }

    // 1) threshold scores, zero bitmasks
    for (int i = tid; i < NB; i += NMS_T) {
        float sc = scores[b * NB + i];
        ss[i] = (sc > CONF_THR) ? sc : NEG_INF;
    }
    for (int t = tid; t < NB * NW; t += NMS_T)
        ((unsigned int*)supp)[t] = 0u;
    if (tid < NW) keepw[tid] = 0u;
    __syncthreads();

    // 2) stable descending rank (== jnp.argsort(-s) stable, tie -> lower index first)
    for (int i = tid; i < NB; i += NMS_T) {
        float si = ss[i];
        int r = 0;
        for (int j = 0; j < NB; ++j) {
            float sj = ss[j];
            r += (sj > si) || (sj == si && j < i);
        }
        sbx[r][0] = boxes[(b * NB + i) * 4 + 0];
        sbx[r][1] = boxes[(b * NB + i) * 4 + 1];
        sbx[r][2] = boxes[(b * NB + i) * 4 + 2];
        sbx[r][3] = boxes[(b * NB + i) * 4 + 3];
        if (si > NEG_INF) atomicOr(&keepw[r >> 5], 1u << (r & 31));
    }
    __syncthreads();

    // 3) suppression matrix: bit j of supp[i] set iff j>i and iou(i,j) > thr
    for (int t = tid; t < NB * NB; t += NMS_T) {
        int i = t / NB, j = t - i * NB;
        if (j <= i) continue;
        float ax1 = sbx[i][0], ay1 = sbx[i][1], ax2 = sbx[i][2], ay2 = sbx[i][3];
        float bx1 = sbx[j][0], by1 = sbx[j][1], bx2 = sbx[j][2], by2 = sbx[j][3];
        float area_a = (ax2 - ax1) * (ay2 - ay1);
        float area_b = (bx2 - bx1) * (by2 - by1);
        float ltx = fmaxf(ax1, bx1), lty = fmaxf(ay1, by1);
        float rbx = fminf(ax2, bx2), rby = fminf(ay2, by2);
        float wx = fmaxf(rbx - ltx, 0.0f), wy = fmaxf(rby - lty, 0.0f);
        float inter = wx * wy;
        float iou = inter / (area_a + area_b - inter + 1e-9f);
        if (iou > IOU_THR) atomicOr(&supp[i][j >> 5], 1u << (j & 31));
    }
    __syncthreads();

    // 4) greedy suppression scan, wave-parallel bitmask form (wave 0).
    if (tid < 64) {
        const int lane = tid;
        unsigned int kpw = (lane < NW) ? keepw[lane] : 0u;
        for (int i = 0; i < NB; ++i) {
            unsigned int wrd = __shfl(kpw, i >> 5, 64);
            if ((wrd >> (i & 31)) & 1u) {
                unsigned int s = (lane < NW) ? supp[i][lane] : 0u;
                kpw &= ~s;
            }
        }
        if (lane < NW) keepw[lane] = kpw;
        int tot = (lane < NW) ? __popc(kpw) : 0;
        for (int off = 32; off; off >>= 1) tot += __shfl_xor(tot, off, 64);
        if (lane == 0) kept_total = tot;
    }
    __syncthreads();

    // 5) stable partition + per-ROI separable pooling metadata
    for (int i = tid; i < NB; i += NMS_T) {
        int w = i >> 5, bt = i & 31;
        int kbit = (keepw[w] >> bt) & 1;
        int pre_kept = 0;
        for (int k = 0; k < w; ++k) pre_kept += __popc(keepw[k]);
        pre_kept += __popc(keepw[w] & ((1u << bt) - 1u));
        int pos = kbit ? pre_kept : (kept_total + (i - pre_kept));
        if (pos >= RSEL) continue;
        if (!kbit) continue;  // record already zeroed -> valid=0

        float* o = ws + (size_t)(b * RSEL + pos) * WSTR;

        float bx1 = sbx[i][0], by1 = sbx[i][1], bx2 = sbx[i][2], by2 = sbx[i][3];
        float dx = bx2 - bx1, dy = by2 - by1;
        float sz = sqrtf(fmaxf(dx * dx + dy * dy, 1e-12f));
        float l  = floorf(4.0f + log2f(sz * (4.0f / 224.0f)));
        l = fminf(fmaxf(l, 2.0f), 5.0f) - 2.0f;
        int lvl = (int)l;
        int H = (lvl == 0) ? 200 : ((lvl == 1) ? 100 : ((lvl == 2) ? 50 : 25));
        float Hf = (float)H;

        o[0] = 1.0f;
        o[1] = l;

        // --- rows: dedupe + weights ---
        int ridx[28]; float rwt[28]; int nr = 0;
        float rh = fmaxf(dy, 1.0f);
        for (int s = 0; s < 14; ++s) {
            float g = (s + 0.5f) * (1.0f / 14.0f);
            float Y = by1 + rh * g;
            bool oob = (Y < -1.0f) || (Y > Hf);
            float yc = fminf(fmaxf(Y, 0.0f), Hf - 1.0f);
            int y0 = (int)floorf(yc);
            int y1i = min(y0 + 1, H - 1);
            float ly = yc - (float)y0;
            float w0 = oob ? 0.0f : (1.0f - ly);
            float w1 = oob ? 0.0f : ly;
            if (w0 != 0.0f) {
                int m = 0; for (; m < nr; ++m) if (ridx[m] == y0) break;
                if (m == nr) { ridx[nr] = y0; rwt[nr] = w0; ++nr; } else rwt[m] += w0;
            }
            if (w1 != 0.0f) {
                int m = 0; for (; m < nr; ++m) if (ridx[m] == y1i) break;
                if (m == nr) { ridx[nr] = y1i; rwt[nr] = w1; ++nr; } else rwt[m] += w1;
            }
        }
        o[2] = (float)nr;
        for (int m = 0; m < nr; ++m) {
            o[8 + m]  = (float)ridx[m];
            o[36 + m] = rwt[m] * (1.0f / 196.0f);
        }

        // --- cols: pass 1, min/max over nonzero-weight grid columns ---
        float rw = fmaxf(dx, 1.0f);
        int xmn = 1 << 30, xmx = -1;
        for (int s = 0; s < 14; ++s) {
            float g = (s + 0.5f) * (1.0f / 14.0f);
            float X = bx1 + rw * g;
            bool oob = (X < -1.0f) || (X > Hf);
            if (oob) continue;
            float xc = fminf(fmaxf(X, 0.0f), Hf - 1.0f);
            int x0 = (int)floorf(xc);
            int x1i = min(x0 + 1, H - 1);
            float lx = xc - (float)x0;
            if ((1.0f - lx) != 0.0f) { xmn = min(xmn, x0);  xmx = max(xmx, x0);  }
            if (lx != 0.0f)          { xmn = min(xmn, x1i); xmx = max(xmx, x1i); }
        }
        int ce = (xmx >= xmn) ? (xmx - xmn + 1) : 0;
        if (ce > 64) ce = 64;   // defensive; analysis bounds ce <= 57

        // window base xs:
        //  lvl<=1 (W=200/100): 4-aligned + end-clamped so [xs, xs+64) is fully
        //  inside the row -> pool fast path can do unconditional aligned float4.
        //  xs = min(xmn & ~3, W-64); coverage proof: xmn - xs + ce <= 64.
        int xs, ce_st;
        if (ce <= 0)       { xs = 0;   ce_st = 0; }
        else if (lvl <= 1) {
            xs = xmn & ~3;
            if (xs > H - 64) xs = H - 64;   // H-64 is a multiple of 4 (136 / 36)
            ce_st = xmn - xs + ce;
            if (ce_st > 64) ce_st = 64;
        } else             { xs = xmn; ce_st = ce; }
        o[3] = (float)ce_st;
        o[4] = (float)xs;

        // --- cols: pass 2, accumulate dense column weights (relative to xs) ---
        if (ce > 0) {
            for (int s = 0; s < 14; ++s) {
                float g = (s + 0.5f) * (1.0f / 14.0f);
                float X = bx1 + rw * g;
                bool oob = (X < -1.0f) || (X > Hf);
                if (oob) continue;
                float xc = fminf(fmaxf(X, 0.0f), Hf - 1.0f);
                int x0 = (int)floorf(xc);
                int x1i = min(x0 + 1, H - 1);
                float lx = xc - (float)x0;
                float w0 = 1.0f - lx;
                if (w0 != 0.0f) { int p = x0 - xs;  if (p >= 0 && p < 64) o[64 + p] += w0; }
                if (lx != 0.0f) { int p = x1i - xs; if (p >= 0 && p < 64) o[64 + p] += lx; }
            }
        }
    }
}

// grid: (BB*RSEL, 4); block: 256. Block (br, cg) handles channels [cg*64, cg*64+64).
// Wave w accumulates 16 channels.
// Fast path (lvl 0/1): lane = h*16 + c4; each lane loads an aligned float4
//   (cols 4c4..4c4+3 of row r+h, rel. to xs) -> 16 B/lane coalescing, 4 rows per
//   round, col weights folded per element. xs construction in nms_kernel
//   guarantees alignment and no row overrun, so no per-element guards needed.
// Slow path (lvl 2/3, W=50/25): scalar row-packed path (pack = 4/2/1 by ce).
__global__ __launch_bounds__(256) void pool_kernel(
    const float* __restrict__ f0, const float* __restrict__ f1,
    const float* __restrict__ f2, const float* __restrict__ f3,
    const float* __restrict__ ws, float* __restrict__ out)
{
    const int br   = blockIdx.x;           // b*RSEL + r
    const int cg   = blockIdx.y;           // 0..3
    const int b    = br / RSEL;
    const int tid  = threadIdx.x;
    const int lane = tid & 63;
    const int wv   = tid >> 6;

    __shared__ __align__(16) float smeta[WSTR];
    for (int t = tid; t < WSTR; t += 256) smeta[t] = ws[(size_t)br * WSTR + t];
    __syncthreads();

    const size_t obase = (size_t)br * NCH + (size_t)cg * 64;
    if (smeta[0] == 0.0f) {
        if (tid < 64) out[obase + tid] = 0.0f;
        return;
    }

    const int lvl = (int)smeta[1];
    const int nr  = (int)smeta[2];
    const int ce  = (int)smeta[3];
    const int xs  = (int)smeta[4];

    const float* feat; int H;
    if      (lvl == 0) { feat = f0; H = 200; }
    else if (lvl == 1) { feat = f1; H = 100; }
    else if (lvl == 2) { feat = f2; H = 50;  }
    else               { feat = f3; H = 25;  }
    const int W = H;
    const size_t cstr = (size_t)H * W;

    const int c0 = cg * 64 + wv * 16;

    float acc[16];
#pragma unroll
    for (int u = 0; u < 16; ++u) acc[u] = 0.0f;

    float wxl;  // post-reduction per-lane column factor (1.0 on the fast path)

    if (lvl <= 1) {
        // ---- float4 fast path ----
        const int c4 = lane & 15;
        const int h  = lane >> 4;          // 4 row-slots per round
        const float4 wv4 = *(const float4*)&smeta[64 + 4 * c4];  // aligned LDS b128
        const bool cld = (4 * c4) < ce;    // skip all-zero-weight lanes (saves BW)
        const int W4 = W >> 2;
        const size_t cstr4 = cstr >> 2;
        const float4* fb4 = (const float4*)(feat + ((size_t)b * NCH + c0) * cstr + xs) + c4;

        for (int r = 0; r < nr; r += 4) {
            const int  rh  = r + h;
            const bool rok = (rh < nr);
            const int  row = rok ? (int)smeta[8 + rh] : 0;
            const float rwt = rok ? smeta[36 + rh] : 0.0f;
            const float4* p = fb4 + (size_t)row * W4;
#pragma unroll
            for (int u = 0; u < 16; ++u) {
                float4 v = make_float4(0.0f, 0.0f, 0.0f, 0.0f);
                if (cld && rok) v = p[(size_t)u * cstr4];
                float s = v.x * wv4.x;
                s = fmaf(v.y, wv4.y, s);
                s = fmaf(v.z, wv4.z, s);
                s = fmaf(v.w, wv4.w, s);
                acc[u] = fmaf(rwt, s, acc[u]);
            }
        }
        wxl = 1.0f;
    } else {
        // ---- scalar row-packed path (small maps, mostly-OOB ROIs) ----
        const int pack = (ce <= 16) ? 4 : ((ce <= 32) ? 2 : 1);
        const int cpl  = 64 / pack;            // cols per row-slot: 16/32/64
        const int c    = lane & (cpl - 1);
        const int h    = lane / cpl;           // row slot within round

        const bool  cld = (c < ce);
        wxl = cld ? smeta[64 + c] : 0.0f;

        const float* fb = feat + ((size_t)b * NCH + c0) * cstr + xs + c;

        for (int r = 0; r < nr; r += pack) {
            const int  rh   = r + h;
            const bool rok  = (rh < nr);
            const int  row  = rok ? (int)smeta[8 + rh] : 0;
            const float rwt = rok ? smeta[36 + rh] : 0.0f;
            const float* p  = fb + (size_t)row * W;
#pragma unroll
            for (int u = 0; u < 16; ++u) {
                float v = 0.0f;
                if (cld) v = p[u * cstr];
                acc[u] = fmaf(rwt, v, acc[u]);
            }
        }
    }

#pragma unroll
    for (int u = 0; u < 16; ++u) {
        float a = acc[u] * wxl;
        for (int off = 32; off; off >>= 1) a += __shfl_xor(a, off, 64);
        if (lane == 0) out[obase + wv * 16 + u] = a;
    }
}

extern "C" void kernel_launch(void* const* d_in, const int* in_sizes, int n_in,
                              void* d_out, int out_size, void* d_ws, size_t ws_size,
                              hipStream_t stream) {
    const float* boxes  = (const float*)d_in[0];
    const float* scores = (const float*)d_in[1];
    const float* f0     = (const float*)d_in[2];
    const float* f1     = (const float*)d_in[3];
    const float* f2     = (const float*)d_in[4];
    const float* f3     = (const float*)d_in[5];
    float* ws  = (float*)d_ws;
    float* out = (float*)d_out;

    nms_kernel<<<BB, NMS_T, 0, stream>>>(boxes, scores, ws);
    dim3 pgrid(BB * RSEL, 4);
    pool_kernel<<<pgrid, 256, 0, stream>>>(f0, f1, f2, f3, ws, out);
}